// Round 1
// 61.717 us; speedup vs baseline: 1.0015x; 1.0015x over previous
//
#include <hip/hip_runtime.h>

// SConv2d with MAJ3 tree reduction.
// x: (8, 27, 32, 32) f32, w: (27, 27, 3, 3) f32 -> out: (8, 27, 32, 32) f32.
// s-domain trick: (x+1)/2 ... 2r-1 cancels between tree levels; convert once
// at the leaves (s = (0.5*x)*w + 0.5, x prescaled) and once at the root.
//
// R7 = R3/R6 structure (best measured 61.8 us; neighbors in the
// (px/thread, split, oc-share) space all regress) with ONE change:
// the two per-thread pixel streams (a = ow0, b = ow0+1) are packed into
// 2-wide float vectors so the whole maj3 tree emits v_pk_fma_f32 /
// v_pk_mul_f32 / v_pk_add_f32 instead of scalar pairs. The two trees are
// independent leaf-to-root (they only separate at the part[] store), so
// packing is exact — same association order, same numerics per lane.
// Per-thread VALU issue slots drop ~480 -> ~300; LDS traffic, layout,
// grid (448 x 768 = 5.25 waves/SIMD), and barriers are unchanged.

#define HH 32
#define WW 32
#define CC 27
#define OCC 27

typedef float v2f __attribute__((ext_vector_type(2)));

__device__ __forceinline__ v2f splat2(float s) { v2f r; r.x = s; r.y = s; return r; }

// majority gate on s-domain values: ab + ac + bc - 2abc, packed over the
// two pixel streams: v_pk_mul + v_pk_add + 2x v_pk_fma (4 issue slots for
// what was 8 scalar ones).
__device__ __forceinline__ v2f maj3v(v2f a, v2f b, v2f c) {
    v2f ab = a * b;
    v2f t  = __builtin_elementwise_fma(splat2(-2.0f), ab, a + b);  // a+b-2ab
    return __builtin_elementwise_fma(c, t, ab);                    // ab + c*t
}

// scalar variant for the phase-3 combine (one px/thread there)
__device__ __forceinline__ float maj3(float a, float b, float c) {
    float ab = a * b;
    float t  = fmaf(-2.0f, ab, a + b);
    return fmaf(c, t, ab);
}

// tile: 27 ch x 6 rows x stride 36 floats (23.3 KB), prescaled 0.5, pad -0.5.
// partials: 4 oc x 128 px x 3 c3 floats (6 KB).
__global__ __launch_bounds__(768) void sconv_maj_kernel(
    const float* __restrict__ x, const float* __restrict__ w, float* __restrict__ out)
{
    __shared__ float smem[27 * 6 * 36 + 4 * 128 * 3];   // 29,472 B
    float* tile = smem;
    float* part = smem + 27 * 6 * 36;

    const int b    = blockIdx.x;
    const int rg   = b & 7;            // 8 row-groups of 4 output rows
    const int rest = b >> 3;
    const int ocg  = rest % 7;         // 7 groups of 4 oc (last has 3)
    const int n    = rest / 7;
    const int tid  = threadIdx.x;

    const float* __restrict__ xb = x + n * (CC * HH * WW);

    // ---- stage prescaled, padded tile (all 768 threads) ----
    {
        const int lane = tid & 31;     // column 0..31
        const int team = tid >> 5;     // 24 row-teams
        for (int R = team; R < 162; R += 24) {    // R = c*6 + tr
            const int c  = R / 6;
            const int tr = R - c * 6;
            const int ih = rg * 4 + tr - 1;
            float v = -0.5f;
            if ((unsigned)ih < 32u) v = 0.5f * xb[c * (HH * WW) + ih * WW + lane];
            tile[R * 36 + 1 + lane] = v;
        }
        for (int i = tid; i < 324; i += 768) {    // col 0 and col 33 borders
            const int R = i >> 1;
            tile[R * 36 + ((i & 1) ? 33 : 0)] = -0.5f;
        }
    }
    __syncthreads();

    // ---- partial trees: wave = (oc_local, c3); thread = 2 adjacent px ----
    const int wavei    = __builtin_amdgcn_readfirstlane(tid >> 6);  // 0..11, SGPR
    const int oc_local = wavei / 3;
    const int sub3     = wavei - oc_local * 3;       // c3 digit, scalar
    const int oc       = ocg * 4 + oc_local;         // scalar -> s_load weights
    const int lt  = tid & 63;
    const int pr  = lt >> 4;           // local pixel row 0..3
    const int ow0 = (lt & 15) << 1;    // even column pair ow0, ow0+1

    if (oc < OCC) {
        const float* __restrict__ wp = w + oc * 243 + sub3 * 81;  // 9 channels

        v2f l4[3];
#pragma unroll
        for (int c2 = 0; c2 < 3; ++c2) {
            v2f l3[3];
#pragma unroll
            for (int c1 = 0; c1 < 3; ++c1) {
                const int c  = sub3 * 9 + c2 * 3 + c1;   // absolute channel
                const int cw = c2 * 3 + c1;              // within-c3 index
                const float* trow = &tile[(c * 6 + pr) * 36 + ow0];
                v2f rv[3];
#pragma unroll
                for (int kh = 0; kh < 3; ++kh) {
                    // taps ow0..ow0+3 (8B-aligned pairs)
                    const float2 u0 = *(const float2*)(trow + kh * 36);
                    const float2 u1 = *(const float2*)(trow + kh * 36 + 2);
                    const float w0 = wp[cw * 9 + kh * 3 + 0];
                    const float w1 = wp[cw * 9 + kh * 3 + 1];
                    const float w2 = wp[cw * 9 + kh * 3 + 2];
                    // pixel-pair tap vectors: lane0 = px a (ow0), lane1 = px b (ow0+1)
                    v2f t0; t0.x = u0.x; t0.y = u0.y;
                    v2f t1; t1.x = u0.y; t1.y = u1.x;
                    v2f t2; t2.x = u1.x; t2.y = u1.y;
                    // leaf: s = (x*w+1)/2 = (0.5x)*w + 0.5; then level 1: kw
                    v2f s0 = __builtin_elementwise_fma(t0, splat2(w0), splat2(0.5f));
                    v2f s1 = __builtin_elementwise_fma(t1, splat2(w1), splat2(0.5f));
                    v2f s2 = __builtin_elementwise_fma(t2, splat2(w2), splat2(0.5f));
                    rv[kh] = maj3v(s0, s1, s2);
                }
                l3[c1] = maj3v(rv[0], rv[1], rv[2]);     // level 2: kh
            }
            l4[c2] = maj3v(l3[0], l3[1], l3[2]);         // level 3: c1
        }
        const v2f pv = maj3v(l4[0], l4[1], l4[2]);       // level 4: c2 (c3-partial)

        const int base = (oc_local * 128 + pr * 32 + ow0) * 3 + sub3;
        part[base]     = pv.x;
        part[base + 3] = pv.y;
    }
    __syncthreads();

    // ---- combine: level 5 over c3 + back-convert; 512 threads, 1 px each ----
    if (tid < 512) {
        const int ocl = tid >> 7;
        const int px  = tid & 127;
        const int oc2 = ocg * 4 + ocl;
        if (oc2 < OCC) {
            const int b0 = (ocl * 128 + px) * 3;
            const float y = fmaf(2.0f, maj3(part[b0], part[b0 + 1], part[b0 + 2]), -1.0f);
            const int oh = rg * 4 + (px >> 5);
            const int ow = px & 31;
            out[(((n * OCC + oc2) * HH) + oh) * WW + ow] = y;
        }
    }
}

extern "C" void kernel_launch(void* const* d_in, const int* in_sizes, int n_in,
                              void* d_out, int out_size, void* d_ws, size_t ws_size,
                              hipStream_t stream) {
    const float* x = (const float*)d_in[0];
    const float* w = (const float*)d_in[1];
    float* out = (float*)d_out;
    // grid: 8 n * 7 oc-groups * 8 row-groups = 448 blocks, 768 threads (12 waves)
    sconv_maj_kernel<<<dim3(8 * 7 * 8), dim3(768), 0, stream>>>(x, w, out);
}

// Round 2
// 60.525 us; speedup vs baseline: 1.0212x; 1.0197x over previous
//
#include <hip/hip_runtime.h>

// SConv2d with MAJ3 tree reduction.
// x: (8, 27, 32, 32) f32, w: (27, 27, 3, 3) f32 -> out: (8, 27, 32, 32) f32.
// s-domain trick: (x+1)/2 ... 2r-1 cancels between tree levels; convert once
// at the leaves (s = (0.5*x)*w + 0.5, x prescaled) and once at the root.
//
// R8 = R3/R6/R7 structure (best 61.7-61.8 us; structural neighbors in the
// (px/thread, split, oc-share) space all regress; R7 showed VALU count is
// NOT the bottleneck: packed maj3 tree = null delta). This round targets
// latency, not throughput:
//   (i)  staging loads vectorized: 7 predicated scalar loads/thread ->
//        2 float4 loads (+ hoisted row math). Fewer outstanding-VMEM
//        events, no per-iteration R/6 magic-mul.
//   (ii) s_setprio(1) around the phase-2 tree: blocks are phase-staggered
//        (one stages while the other computes), so compute waves get issue
//        priority over staging waves (T5 regime: role-split waves).
// Grid, LDS layout, tree association identical -> same numerics.

#define HH 32
#define WW 32
#define CC 27
#define OCC 27

typedef float v2f __attribute__((ext_vector_type(2)));

__device__ __forceinline__ v2f splat2(float s) { v2f r; r.x = s; r.y = s; return r; }

// majority gate on s-domain values: ab + ac + bc - 2abc, packed over the
// two pixel streams.
__device__ __forceinline__ v2f maj3v(v2f a, v2f b, v2f c) {
    v2f ab = a * b;
    v2f t  = __builtin_elementwise_fma(splat2(-2.0f), ab, a + b);  // a+b-2ab
    return __builtin_elementwise_fma(c, t, ab);                    // ab + c*t
}

// scalar variant for the phase-3 combine (one px/thread there)
__device__ __forceinline__ float maj3(float a, float b, float c) {
    float ab = a * b;
    float t  = fmaf(-2.0f, ab, a + b);
    return fmaf(c, t, ab);
}

// tile: 27 ch x 6 rows x stride 36 floats (23.3 KB), prescaled 0.5, pad -0.5.
// partials: 4 oc x 128 px x 3 c3 floats (6 KB).
__global__ __launch_bounds__(768) void sconv_maj_kernel(
    const float* __restrict__ x, const float* __restrict__ w, float* __restrict__ out)
{
    __shared__ float smem[27 * 6 * 36 + 4 * 128 * 3];   // 29,472 B
    float* tile = smem;
    float* part = smem + 27 * 6 * 36;

    const int b    = blockIdx.x;
    const int rg   = b & 7;            // 8 row-groups of 4 output rows
    const int rest = b >> 3;
    const int ocg  = rest % 7;         // 7 groups of 4 oc (last has 3)
    const int n    = rest / 7;
    const int tid  = threadIdx.x;

    const float* __restrict__ xb = x + n * (CC * HH * WW);

    // ---- stage prescaled, padded tile: 162 rows x 8 float4-quads ----
    // slot s in [0,1296): R = s>>3 (row = c*6+tr), q = s&7 (cols 4q..4q+3)
    {
#pragma unroll
        for (int it = 0; it < 2; ++it) {
            const int s = tid + it * 768;
            if (s < 162 * 8) {
                const int R  = s >> 3;
                const int q  = s & 7;
                const int c  = R / 6;
                const int tr = R - c * 6;
                const int ih = rg * 4 + tr - 1;
                float4 v = make_float4(-0.5f, -0.5f, -0.5f, -0.5f);
                if ((unsigned)ih < 32u) {
                    const float4 u = *(const float4*)(xb + c * (HH * WW) + ih * WW + q * 4);
                    v.x = 0.5f * u.x; v.y = 0.5f * u.y;
                    v.z = 0.5f * u.z; v.w = 0.5f * u.w;
                }
                float* d = &tile[R * 36 + 1 + q * 4];
                d[0] = v.x; d[1] = v.y; d[2] = v.z; d[3] = v.w;
            }
        }
        if (tid < 324) {                           // col 0 and col 33 borders
            const int R = tid >> 1;
            tile[R * 36 + ((tid & 1) ? 33 : 0)] = -0.5f;
        }
    }
    __syncthreads();

    // ---- partial trees: wave = (oc_local, c3); thread = 2 adjacent px ----
    const int wavei    = __builtin_amdgcn_readfirstlane(tid >> 6);  // 0..11, SGPR
    const int oc_local = wavei / 3;
    const int sub3     = wavei - oc_local * 3;       // c3 digit, scalar
    const int oc       = ocg * 4 + oc_local;         // scalar -> s_load weights
    const int lt  = tid & 63;
    const int pr  = lt >> 4;           // local pixel row 0..3
    const int ow0 = (lt & 15) << 1;    // even column pair ow0, ow0+1

    if (oc < OCC) {
        const float* __restrict__ wp = w + oc * 243 + sub3 * 81;  // 9 channels

        __builtin_amdgcn_s_setprio(1);             // favor compute waves over
                                                   // the co-resident block's
                                                   // staging waves
        v2f l4[3];
#pragma unroll
        for (int c2 = 0; c2 < 3; ++c2) {
            v2f l3[3];
#pragma unroll
            for (int c1 = 0; c1 < 3; ++c1) {
                const int c  = sub3 * 9 + c2 * 3 + c1;   // absolute channel
                const int cw = c2 * 3 + c1;              // within-c3 index
                const float* trow = &tile[(c * 6 + pr) * 36 + ow0];
                v2f rv[3];
#pragma unroll
                for (int kh = 0; kh < 3; ++kh) {
                    // taps ow0..ow0+3 (8B-aligned pairs)
                    const float2 u0 = *(const float2*)(trow + kh * 36);
                    const float2 u1 = *(const float2*)(trow + kh * 36 + 2);
                    const float w0 = wp[cw * 9 + kh * 3 + 0];
                    const float w1 = wp[cw * 9 + kh * 3 + 1];
                    const float w2 = wp[cw * 9 + kh * 3 + 2];
                    // pixel-pair tap vectors: lane0 = px a (ow0), lane1 = px b (ow0+1)
                    v2f t0; t0.x = u0.x; t0.y = u0.y;
                    v2f t1; t1.x = u0.y; t1.y = u1.x;
                    v2f t2; t2.x = u1.x; t2.y = u1.y;
                    // leaf: s = (x*w+1)/2 = (0.5x)*w + 0.5; then level 1: kw
                    v2f s0 = __builtin_elementwise_fma(t0, splat2(w0), splat2(0.5f));
                    v2f s1 = __builtin_elementwise_fma(t1, splat2(w1), splat2(0.5f));
                    v2f s2 = __builtin_elementwise_fma(t2, splat2(w2), splat2(0.5f));
                    rv[kh] = maj3v(s0, s1, s2);
                }
                l3[c1] = maj3v(rv[0], rv[1], rv[2]);     // level 2: kh
            }
            l4[c2] = maj3v(l3[0], l3[1], l3[2]);         // level 3: c1
        }
        const v2f pv = maj3v(l4[0], l4[1], l4[2]);       // level 4: c2 (c3-partial)
        __builtin_amdgcn_s_setprio(0);

        const int base = (oc_local * 128 + pr * 32 + ow0) * 3 + sub3;
        part[base]     = pv.x;
        part[base + 3] = pv.y;
    }
    __syncthreads();

    // ---- combine: level 5 over c3 + back-convert; 512 threads, 1 px each ----
    if (tid < 512) {
        const int ocl = tid >> 7;
        const int px  = tid & 127;
        const int oc2 = ocg * 4 + ocl;
        if (oc2 < OCC) {
            const int b0 = (ocl * 128 + px) * 3;
            const float y = fmaf(2.0f, maj3(part[b0], part[b0 + 1], part[b0 + 2]), -1.0f);
            const int oh = rg * 4 + (px >> 5);
            const int ow = px & 31;
            out[(((n * OCC + oc2) * HH) + oh) * WW + ow] = y;
        }
    }
}

extern "C" void kernel_launch(void* const* d_in, const int* in_sizes, int n_in,
                              void* d_out, int out_size, void* d_ws, size_t ws_size,
                              hipStream_t stream) {
    const float* x = (const float*)d_in[0];
    const float* w = (const float*)d_in[1];
    float* out = (float*)d_out;
    // grid: 8 n * 7 oc-groups * 8 row-groups = 448 blocks, 768 threads (12 waves)
    sconv_maj_kernel<<<dim3(8 * 7 * 8), dim3(768), 0, stream>>>(x, w, out);
}